// Round 2
// baseline (875.362 us; speedup 1.0000x reference)
//
#include <hip/hip_runtime.h>
#include <hip/hip_bf16.h>
#include <stdint.h>

// Problem: B=32, T=2048, D=1024, U=1024, all fp32 in/out.
// out = [context 32*1024, attention_weights 32*2048]
//
// ws layout:
//   [0, 2MB)           W1t bf16  [U][D]  (transposed W1)
//   [2MB, +128KB)      qp2 fp32  [B][U]  = query@W2 + b2 + b1
//   [2MB+128KB,+256KB) score fp32 [B][T]
#define WS_W1T   0
#define WS_QP2   2097152
#define WS_SCORE (2097152 + 131072)

typedef __attribute__((ext_vector_type(8))) short bf16x8;
typedef __attribute__((ext_vector_type(4))) float f32x4;

__device__ inline uint16_t f2b(float f) {
    __hip_bfloat16 h = __float2bfloat16(f);
    return *reinterpret_cast<uint16_t*>(&h);
}

// ---------------- Kernel 1: W1 [D][U] fp32 -> W1t [U][D] bf16 (+ zero qp2) ----
__global__ __launch_bounds__(256) void k_w1t(const float* __restrict__ W1,
                                             __hip_bfloat16* __restrict__ W1t,
                                             float* __restrict__ qp2) {
    __shared__ __hip_bfloat16 tile[64][72];
    if (blockIdx.x < 128) qp2[blockIdx.x * 256 + threadIdx.x] = 0.f;
    int tu = blockIdx.x & 15, tk = blockIdx.x >> 4;
    int c = threadIdx.x & 63;
    int rb = threadIdx.x >> 6;  // 0..3
    #pragma unroll
    for (int i = 0; i < 16; ++i) {
        int kl = i * 4 + rb;
        tile[kl][c] = __float2bfloat16(W1[(size_t)(tk * 64 + kl) * 1024 + tu * 64 + c]);
    }
    __syncthreads();
    #pragma unroll
    for (int i = 0; i < 16; ++i) {
        int ul = i * 4 + rb;
        W1t[(size_t)(tu * 64 + ul) * 1024 + tk * 64 + c] = tile[c][ul];
    }
}

// ---------------- Kernel 2: qp2[b][u] += sum_d query[b,d]*W2[d,u] (+biases) ---
__global__ __launch_bounds__(256) void k_qp(const float* __restrict__ query,
                                            const float* __restrict__ W2,
                                            const float* __restrict__ b1,
                                            const float* __restrict__ b2,
                                            float* __restrict__ qp2) {
    int b = blockIdx.x >> 3, seg = blockIdx.x & 7;
    int u = threadIdx.x * 4;
    float4 a = {0.f, 0.f, 0.f, 0.f};
    if (seg == 0) {
        a.x = b1[u] + b2[u];     a.y = b1[u+1] + b2[u+1];
        a.z = b1[u+2] + b2[u+2]; a.w = b1[u+3] + b2[u+3];
    }
    const float* q  = query + b * 1024 + seg * 128;
    const float* Wp = W2 + (size_t)seg * 128 * 1024 + u;
    #pragma unroll 8
    for (int d = 0; d < 128; ++d) {
        float qd = q[d];
        float4 wv = *(const float4*)(Wp + (size_t)d * 1024);
        a.x += qd * wv.x; a.y += qd * wv.y; a.z += qd * wv.z; a.w += qd * wv.w;
    }
    float* o = qp2 + b * 1024 + u;
    atomicAdd(o + 0, a.x); atomicAdd(o + 1, a.y);
    atomicAdd(o + 2, a.z); atomicAdd(o + 3, a.w);
}

// ---------------- Kernel 3: fused score = tanh(values@W1 + qp2) @ V ----------
// Grid 1024 = 32 b * 32 row-tiles of 64. Block 512 (8 waves, 2/SIMD).
// A (values tile) resident in LDS: 64 rows x 1024 k bf16, 16B-chunk XOR swizzle.
// B (W1t) streamed DIRECTLY from global (L2-resident, 2MB) into fragments:
//   one dwordx4 per fragment -> zero barriers in the K-loop.
// Wave tiling: w&3 = u-quarter (64 u), w>>2 = row-half (32 rows); (rt,ct)=(2,4).
__global__ __launch_bounds__(512) void k_score(
        const float* __restrict__ values, const __hip_bfloat16* __restrict__ W1t,
        const float* __restrict__ qp2, const float* __restrict__ V,
        float* __restrict__ score) {
    extern __shared__ char smem[];
    uint16_t* Al = (uint16_t*)smem;             // 64 x 1024 bf16 (swizzled)
    float* red = (float*)(smem + 131072);       // [4 u-quarters][64 rows]

    const int tid = threadIdx.x;
    const int lane = tid & 63, w = tid >> 6;
    const int quad = lane >> 4, l15 = lane & 15;
    const int uq = w & 3, rh = w >> 2;
    const int b = blockIdx.x >> 5, trow0 = (blockIdx.x & 31) << 6;

    // ---- stage A: values[b, trow0..+64, :] fp32 -> bf16 LDS (once) ----
    const float* Ag = values + (size_t)(b * 2048 + trow0) * 1024;
    #pragma unroll
    for (int i = 0; i < 16; ++i) {
        int id = i * 512 + tid;
        int row = id >> 7, c = id & 127;       // chunk = 8 elems = 16B LDS / 32B glb
        const float* src = Ag + (size_t)row * 1024 + c * 8;
        float4 v0 = *(const float4*)src;
        float4 v1 = *(const float4*)(src + 4);
        union { uint16_t h[8]; int4 v; } pk;
        pk.h[0]=f2b(v0.x); pk.h[1]=f2b(v0.y); pk.h[2]=f2b(v0.z); pk.h[3]=f2b(v0.w);
        pk.h[4]=f2b(v1.x); pk.h[5]=f2b(v1.y); pk.h[6]=f2b(v1.z); pk.h[7]=f2b(v1.w);
        int pos = (c & 112) | ((c & 15) ^ (row & 15));
        *(int4*)(Al + (size_t)row * 1024 + pos * 8) = pk.v;
    }
    __syncthreads();   // the ONLY barrier before the final reduction

    float srow[2][4];
    #pragma unroll
    for (int rt = 0; rt < 2; ++rt)
        #pragma unroll
        for (int r = 0; r < 4; ++r) srow[rt][r] = 0.f;

    // per-lane B pointer core: row u0+ct*16+l15, byte offset ks*64 + quad*16
    const __hip_bfloat16* Bl = W1t + (size_t)l15 * 1024 + quad * 8;

    for (int p = 0; p < 4; ++p) {
        const int u0 = p * 256 + uq * 64;
        const __hip_bfloat16* Bp = Bl + (size_t)u0 * 1024;
        f32x4 acc[2][4];
        #pragma unroll
        for (int rt = 0; rt < 2; ++rt)
            #pragma unroll
            for (int ct = 0; ct < 4; ++ct) acc[rt][ct] = (f32x4){0.f,0.f,0.f,0.f};

        #pragma unroll 4
        for (int ks = 0; ks < 32; ++ks) {
            int cb = ks * 4 + quad;
            int pos = (cb & 112) | ((cb & 15) ^ l15);
            bf16x8 af[2], bfr[4];
            #pragma unroll
            for (int rt = 0; rt < 2; ++rt) {
                int row = rh * 32 + rt * 16 + l15;
                af[rt] = *(bf16x8*)(Al + row * 1024 + pos * 8);
            }
            #pragma unroll
            for (int ct = 0; ct < 4; ++ct)
                bfr[ct] = *(const bf16x8*)(Bp + (size_t)(ct * 16) * 1024 + ks * 32);
            #pragma unroll
            for (int rt = 0; rt < 2; ++rt)
                #pragma unroll
                for (int ct = 0; ct < 4; ++ct)
                    acc[rt][ct] = __builtin_amdgcn_mfma_f32_16x16x32_bf16(
                        af[rt], bfr[ct], acc[rt][ct], 0, 0, 0);
        }

        // epilogue: tanh(acc + qp2[u]) * V[u], accumulate per-lane row partials
        #pragma unroll
        for (int ct = 0; ct < 4; ++ct) {
            int u = u0 + ct * 16 + l15;
            float qv = qp2[b * 1024 + u];
            float vv = V[u];
            #pragma unroll
            for (int rt = 0; rt < 2; ++rt)
                #pragma unroll
                for (int r = 0; r < 4; ++r) {
                    float x = acc[rt][ct][r] + qv;
                    float e = __expf(2.f * x);
                    float t = 1.f - 2.f * __builtin_amdgcn_rcpf(1.f + e);
                    srow[rt][r] += t * vv;
                }
        }
    }

    // reduce the u-dimension: over the 16 lanes (l15) then over u-quarters
    #pragma unroll
    for (int rt = 0; rt < 2; ++rt)
        #pragma unroll
        for (int r = 0; r < 4; ++r) {
            float s = srow[rt][r];
            s += __shfl_xor(s, 1, 64);
            s += __shfl_xor(s, 2, 64);
            s += __shfl_xor(s, 4, 64);
            s += __shfl_xor(s, 8, 64);
            srow[rt][r] = s;
        }
    if (l15 == 0) {
        #pragma unroll
        for (int rt = 0; rt < 2; ++rt)
            #pragma unroll
            for (int r = 0; r < 4; ++r)
                red[uq * 64 + rh * 32 + rt * 16 + quad * 4 + r] = srow[rt][r];
    }
    __syncthreads();
    if (tid < 64) {
        float s = red[tid] + red[64 + tid] + red[128 + tid] + red[192 + tid];
        score[b * 2048 + trow0 + tid] = s;
    }
}

// ---------------- Kernel 4: softmax over T per b; also zero context ----------
__global__ __launch_bounds__(256) void k_softmax(const float* __restrict__ score,
                                                 float* __restrict__ out) {
    __shared__ float red[8];
    int b = blockIdx.x, tid = threadIdx.x;
    *(float4*)(out + b * 1024 + tid * 4) = make_float4(0.f, 0.f, 0.f, 0.f);
    float s[8]; float m = -1e30f;
    #pragma unroll
    for (int j = 0; j < 8; ++j) {
        s[j] = score[b * 2048 + j * 256 + tid];
        m = fmaxf(m, s[j]);
    }
    for (int off = 32; off; off >>= 1) m = fmaxf(m, __shfl_xor(m, off, 64));
    if ((tid & 63) == 0) red[tid >> 6] = m;
    __syncthreads();
    m = fmaxf(fmaxf(red[0], red[1]), fmaxf(red[2], red[3]));
    float sum = 0.f;
    #pragma unroll
    for (int j = 0; j < 8; ++j) { s[j] = __expf(s[j] - m); sum += s[j]; }
    for (int off = 32; off; off >>= 1) sum += __shfl_xor(sum, off, 64);
    if ((tid & 63) == 0) red[4 + (tid >> 6)] = sum;
    __syncthreads();
    sum = red[4] + red[5] + red[6] + red[7];
    float inv = __builtin_amdgcn_rcpf(sum);
    #pragma unroll
    for (int j = 0; j < 8; ++j)
        out[32768 + b * 2048 + j * 256 + tid] = s[j] * inv;
}

// ---------------- Kernel 5: context[b][d] = sum_t w[b,t]*values[b,t,d] -------
__global__ __launch_bounds__(256) void k_ctx(const float* __restrict__ values,
                                             const float* __restrict__ attw,
                                             float* __restrict__ ctx) {
    __shared__ float wl[128];
    int b = blockIdx.x >> 4, ts = blockIdx.x & 15, tid = threadIdx.x;
    if (tid < 128) wl[tid] = attw[b * 2048 + ts * 128 + tid];
    __syncthreads();
    const float* vb = values + ((size_t)(b * 2048 + ts * 128)) * 1024 + tid * 4;
    float4 a = {0.f, 0.f, 0.f, 0.f};
    #pragma unroll 4
    for (int t = 0; t < 128; ++t) {
        float4 v = *(const float4*)(vb + (size_t)t * 1024);
        float ww = wl[t];
        a.x += ww * v.x; a.y += ww * v.y; a.z += ww * v.z; a.w += ww * v.w;
    }
    float* o = ctx + b * 1024 + tid * 4;
    atomicAdd(o + 0, a.x); atomicAdd(o + 1, a.y);
    atomicAdd(o + 2, a.z); atomicAdd(o + 3, a.w);
}

extern "C" void kernel_launch(void* const* d_in, const int* in_sizes, int n_in,
                              void* d_out, int out_size, void* d_ws, size_t ws_size,
                              hipStream_t stream) {
    const float* query  = (const float*)d_in[0];
    const float* values = (const float*)d_in[1];
    const float* W1 = (const float*)d_in[2];
    const float* b1 = (const float*)d_in[3];
    const float* W2 = (const float*)d_in[4];
    const float* b2 = (const float*)d_in[5];
    const float* V  = (const float*)d_in[6];
    // d_in[7] = bv: adds a constant pre-softmax -> cancels; unused.

    char* ws = (char*)d_ws;
    __hip_bfloat16* W1t = (__hip_bfloat16*)(ws + WS_W1T);
    float* qp2   = (float*)(ws + WS_QP2);
    float* score = (float*)(ws + WS_SCORE);
    float* out = (float*)d_out;

    (void)hipFuncSetAttribute((const void*)k_score,
                              hipFuncAttributeMaxDynamicSharedMemorySize, 135168);

    k_w1t<<<256, 256, 0, stream>>>(W1, W1t, qp2);
    k_qp<<<256, 256, 0, stream>>>(query, W2, b1, b2, qp2);
    k_score<<<1024, 512, 132096, stream>>>(values, W1t, qp2, V, score);
    k_softmax<<<32, 256, 0, stream>>>(score, out);
    k_ctx<<<512, 256, 0, stream>>>(values, out + 32768, out);
}

// Round 3
// 586.720 us; speedup vs baseline: 1.4920x; 1.4920x over previous
//
#include <hip/hip_runtime.h>
#include <hip/hip_bf16.h>
#include <stdint.h>

// Problem: B=32, T=2048, D=1024, U=1024, all fp32 in/out.
// out = [context 32*1024, attention_weights 32*2048]
//
// ws layout:
//   [0, 2MB)            W1f bf16 — W1 packed in MFMA B-fragment order:
//                       frag(ut,ks) = 1KB block; elem(lane,j) =
//                       W1[k = ks*32 + (lane>>4)*8 + j][u = ut*16 + (lane&15)]
//   [2MB, +128KB)       qp2 fp32 [B][U] = query@W2 + b2 + b1
//   [2MB+128KB,+256KB)  score fp32 [B][T]
#define WS_W1F   0
#define WS_QP2   2097152
#define WS_SCORE (2097152 + 131072)

typedef __attribute__((ext_vector_type(8))) short bf16x8;
typedef __attribute__((ext_vector_type(4))) float f32x4;

__device__ inline uint16_t f2b(float f) {
    __hip_bfloat16 h = __float2bfloat16(f);
    return *reinterpret_cast<uint16_t*>(&h);
}

// ---------------- Kernel 1: prep = W1 repack + qp2 + ctx zero ----------------
// blocks 0..255: repack 8 fragments each (2048 fragments of 1KB total)
// blocks 256..287: qp2[b][:] = b1 + b2 + query[b]@W2 (no atomics); zero ctx[b]
__global__ __launch_bounds__(256) void k_prep(const float* __restrict__ W1,
                                              const float* __restrict__ query,
                                              const float* __restrict__ W2,
                                              const float* __restrict__ b1,
                                              const float* __restrict__ b2,
                                              __hip_bfloat16* __restrict__ W1f,
                                              float* __restrict__ qp2,
                                              float* __restrict__ ctx_out) {
    int blk = blockIdx.x, tid = threadIdx.x;
    if (blk < 256) {
        int lane = tid & 63, fi = tid >> 6;
        int l15 = lane & 15, quad = lane >> 4;
        #pragma unroll
        for (int p = 0; p < 2; ++p) {
            int frag = blk * 8 + p * 4 + fi;      // 0..2047
            int ut = frag >> 5, ks = frag & 31;
            union { uint16_t h[8]; int4 v; } pk;
            #pragma unroll
            for (int j = 0; j < 8; ++j) {
                float x = W1[(size_t)(ks * 32 + quad * 8 + j) * 1024 + ut * 16 + l15];
                pk.h[j] = f2b(x);
            }
            *(int4*)((char*)W1f + (size_t)frag * 1024 + lane * 16) = pk.v;
        }
    } else {
        int b = blk - 256;
        int u = tid * 4;
        *(float4*)(ctx_out + b * 1024 + u) = make_float4(0.f, 0.f, 0.f, 0.f);
        float4 a;
        a.x = b1[u] + b2[u];     a.y = b1[u+1] + b2[u+1];
        a.z = b1[u+2] + b2[u+2]; a.w = b1[u+3] + b2[u+3];
        const float* q = query + b * 1024;
        #pragma unroll 8
        for (int d = 0; d < 1024; ++d) {
            float qd = q[d];
            float4 wv = *(const float4*)(W2 + (size_t)d * 1024 + u);
            a.x += qd * wv.x; a.y += qd * wv.y; a.z += qd * wv.z; a.w += qd * wv.w;
        }
        *(float4*)(qp2 + b * 1024 + u) = a;
    }
}

// ---------------- Kernel 2: fused score = tanh(values@W1 + qp2) @ V ----------
// Grid 1024 = 32 b * 32 row-tiles of 64. Block 512 (8 waves, 2/SIMD).
// A resident in LDS (64 rows x 1024 k bf16, XOR-swizzled 16B chunks, 0 conflicts).
// B from global in fragment-packed order: each frag load = base + lane*16,
//   ONE coalesced 1KB segment -> zero barriers, zero address divergence.
// Wave w owns u-stripe [w*128, w*128+128): rt=4 (64 rows), ct=8.
// Register double-buffer af/bf across k-steps.
__global__ __launch_bounds__(512, 1) void k_score(
        const float* __restrict__ values, const __hip_bfloat16* __restrict__ W1f,
        const float* __restrict__ qp2, const float* __restrict__ V,
        float* __restrict__ score) {
    extern __shared__ char smem[];
    uint16_t* Al = (uint16_t*)smem;             // 64 x 1024 bf16 (swizzled)
    float* red = (float*)(smem + 131072);       // [8 stripes][64 rows]

    const int tid = threadIdx.x;
    const int lane = tid & 63, w = tid >> 6;
    const int quad = lane >> 4, l15 = lane & 15;
    const int b = blockIdx.x >> 5, trow0 = (blockIdx.x & 31) << 6;

    // ---- stage A: values[b, trow0..+64, :] fp32 -> bf16 LDS (once) ----
    const float* Ag = values + (size_t)(b * 2048 + trow0) * 1024;
    #pragma unroll
    for (int i = 0; i < 16; ++i) {
        int id = i * 512 + tid;
        int row = id >> 7, c = id & 127;
        const float* src = Ag + (size_t)row * 1024 + c * 8;
        float4 v0 = *(const float4*)src;
        float4 v1 = *(const float4*)(src + 4);
        union { uint16_t h[8]; int4 v; } pk;
        pk.h[0]=f2b(v0.x); pk.h[1]=f2b(v0.y); pk.h[2]=f2b(v0.z); pk.h[3]=f2b(v0.w);
        pk.h[4]=f2b(v1.x); pk.h[5]=f2b(v1.y); pk.h[6]=f2b(v1.z); pk.h[7]=f2b(v1.w);
        int pos = (c & 112) | ((c & 15) ^ (row & 15));
        *(int4*)(Al + (size_t)row * 1024 + pos * 8) = pk.v;
    }
    __syncthreads();   // only barrier before the final reduction

    // per-lane fragment base: frag(ut = w*8 + ct, ks) at byte (ut*32+ks)*1024
    const char* Bbase = (const char*)W1f + (size_t)(w * 8) * 32768 + lane * 16;

    f32x4 acc[4][8];
    #pragma unroll
    for (int rt = 0; rt < 4; ++rt)
        #pragma unroll
        for (int ct = 0; ct < 8; ++ct) acc[rt][ct] = (f32x4){0.f, 0.f, 0.f, 0.f};

    bf16x8 af[2][4], bfr[2][8];
    {   // prologue: ks = 0
        int pos = (quad & 15) ^ l15;   // cb = quad
        #pragma unroll
        for (int rt = 0; rt < 4; ++rt)
            af[0][rt] = *(bf16x8*)(Al + (rt * 16 + l15) * 1024 + pos * 8);
        #pragma unroll
        for (int ct = 0; ct < 8; ++ct)
            bfr[0][ct] = *(const bf16x8*)(Bbase + (size_t)(ct * 32) * 1024);
    }

    #pragma unroll 2
    for (int ks = 0; ks < 32; ++ks) {
        int cur = ks & 1, nxt = cur ^ 1;
        if (ks < 31) {
            int cb = (ks + 1) * 4 + quad;
            int pos = (cb & 112) | ((cb & 15) ^ l15);
            #pragma unroll
            for (int rt = 0; rt < 4; ++rt)
                af[nxt][rt] = *(bf16x8*)(Al + (rt * 16 + l15) * 1024 + pos * 8);
            #pragma unroll
            for (int ct = 0; ct < 8; ++ct)
                bfr[nxt][ct] = *(const bf16x8*)(Bbase + (size_t)(ct * 32 + ks + 1) * 1024);
        }
        #pragma unroll
        for (int rt = 0; rt < 4; ++rt)
            #pragma unroll
            for (int ct = 0; ct < 8; ++ct)
                acc[rt][ct] = __builtin_amdgcn_mfma_f32_16x16x32_bf16(
                    af[cur][rt], bfr[cur][ct], acc[rt][ct], 0, 0, 0);
    }

    // ---- epilogue: tanh(acc + qp2[u]) * V[u], per-lane row partials ----
    float srow[4][4];
    #pragma unroll
    for (int rt = 0; rt < 4; ++rt)
        #pragma unroll
        for (int r = 0; r < 4; ++r) srow[rt][r] = 0.f;
    #pragma unroll
    for (int ct = 0; ct < 8; ++ct) {
        int u = w * 128 + ct * 16 + l15;
        float qv = qp2[b * 1024 + u];
        float vv = V[u];
        #pragma unroll
        for (int rt = 0; rt < 4; ++rt)
            #pragma unroll
            for (int r = 0; r < 4; ++r) {
                float x = acc[rt][ct][r] + qv;
                float e = __expf(2.f * x);
                float t = 1.f - 2.f * __builtin_amdgcn_rcpf(1.f + e);
                srow[rt][r] += t * vv;
            }
    }

    // reduce u: over 16 lanes (l15), then over the 8 wave-stripes via LDS
    #pragma unroll
    for (int rt = 0; rt < 4; ++rt)
        #pragma unroll
        for (int r = 0; r < 4; ++r) {
            float s = srow[rt][r];
            s += __shfl_xor(s, 1, 64);
            s += __shfl_xor(s, 2, 64);
            s += __shfl_xor(s, 4, 64);
            s += __shfl_xor(s, 8, 64);
            srow[rt][r] = s;
        }
    if (l15 == 0) {
        #pragma unroll
        for (int rt = 0; rt < 4; ++rt)
            #pragma unroll
            for (int r = 0; r < 4; ++r)
                red[w * 64 + rt * 16 + quad * 4 + r] = srow[rt][r];
    }
    __syncthreads();
    if (tid < 64) {
        float s = 0.f;
        #pragma unroll
        for (int k = 0; k < 8; ++k) s += red[k * 64 + tid];
        score[b * 2048 + trow0 + tid] = s;
    }
}

// ---------------- Kernel 3: softmax (recomputed per block) + weights + ctx ---
// Grid 512 = 32 b * 16 t-slices of 128. Each block computes the full softmax
// stats for its b (8KB score read, L2-hot), writes its attw slice, then
// accumulates its slice's contribution to context via atomicAdd.
__global__ __launch_bounds__(256) void k_out(const float* __restrict__ values,
                                             const float* __restrict__ score,
                                             float* __restrict__ out) {
    __shared__ float red[8];
    __shared__ float wl[128];
    int b = blockIdx.x >> 4, ts = blockIdx.x & 15, tid = threadIdx.x;
    const float* sc = score + b * 2048;
    float s[8]; float m = -1e30f;
    #pragma unroll
    for (int j = 0; j < 8; ++j) {
        s[j] = sc[j * 256 + tid];
        m = fmaxf(m, s[j]);
    }
    for (int off = 32; off; off >>= 1) m = fmaxf(m, __shfl_xor(m, off, 64));
    if ((tid & 63) == 0) red[tid >> 6] = m;
    __syncthreads();
    m = fmaxf(fmaxf(red[0], red[1]), fmaxf(red[2], red[3]));
    float sum = 0.f;
    #pragma unroll
    for (int j = 0; j < 8; ++j) sum += __expf(s[j] - m);
    for (int off = 32; off; off >>= 1) sum += __shfl_xor(sum, off, 64);
    if ((tid & 63) == 0) red[4 + (tid >> 6)] = sum;
    __syncthreads();
    sum = red[4] + red[5] + red[6] + red[7];
    float inv = __builtin_amdgcn_rcpf(sum);
    if (tid < 128) {
        float wv = __expf(sc[ts * 128 + tid] - m) * inv;
        wl[tid] = wv;
        out[32768 + b * 2048 + ts * 128 + tid] = wv;
    }
    __syncthreads();
    const float* vb = values + ((size_t)(b * 2048 + ts * 128)) * 1024 + tid * 4;
    float4 a = {0.f, 0.f, 0.f, 0.f};
    #pragma unroll 4
    for (int t = 0; t < 128; ++t) {
        float4 v = *(const float4*)(vb + (size_t)t * 1024);
        float ww = wl[t];
        a.x += ww * v.x; a.y += ww * v.y; a.z += ww * v.z; a.w += ww * v.w;
    }
    float* o = out + b * 1024 + tid * 4;
    atomicAdd(o + 0, a.x); atomicAdd(o + 1, a.y);
    atomicAdd(o + 2, a.z); atomicAdd(o + 3, a.w);
}

extern "C" void kernel_launch(void* const* d_in, const int* in_sizes, int n_in,
                              void* d_out, int out_size, void* d_ws, size_t ws_size,
                              hipStream_t stream) {
    const float* query  = (const float*)d_in[0];
    const float* values = (const float*)d_in[1];
    const float* W1 = (const float*)d_in[2];
    const float* b1 = (const float*)d_in[3];
    const float* W2 = (const float*)d_in[4];
    const float* b2 = (const float*)d_in[5];
    const float* V  = (const float*)d_in[6];
    // d_in[7] = bv: adds a constant pre-softmax -> cancels in softmax; unused.

    char* ws = (char*)d_ws;
    __hip_bfloat16* W1f = (__hip_bfloat16*)(ws + WS_W1F);
    float* qp2   = (float*)(ws + WS_QP2);
    float* score = (float*)(ws + WS_SCORE);
    float* out = (float*)d_out;

    (void)hipFuncSetAttribute((const void*)k_score,
                              hipFuncAttributeMaxDynamicSharedMemorySize, 133120);

    k_prep<<<288, 256, 0, stream>>>(W1, query, W2, b1, b2, W1f, qp2, out);
    k_score<<<1024, 512, 133120, stream>>>(values, W1f, qp2, V, score);
    k_out<<<512, 256, 0, stream>>>(values, score, out);
}